// Round 7
// baseline (846.117 us; speedup 1.0000x reference)
//
#include <hip/hip_runtime.h>

// LightGCN on MI355X (gfx950). Round 15.
// R14 post-mortem: row-per-oct cut VALU (54->30%) but FETCH 239->293MB — per-row
// col-sorted streams + 2.5 dispatch rounds desync the band sweep (R13's 239 came
// from og-grouped joint band order + full residency). R15 synthesis: keep R13's
// og=4-rows band-sorted all-resident structure, make routing STATIC by
// TRANSPOSE-PAD: partBF emits og edges at slot i*4+k (edge i of row k), each row
// padded to the og's max degree with zero-words (col=0,val=0 -> x[0]*0, L2-hot,
// harmless). spmm loads 4 edges as ONE uint4, static row routing: 8 useful
// FMAs/edge, no cndmask. Pad ~+19% slots (FMA only), wave divergence ~14%.
// __launch_bounds__(256,5) keeps all 1172 blocks resident (sweep in phase).
// New: deg[] histogram + ogmax + ogscan -> ogptr; fin memset for pads;
// colscan2/bptr/rowptr deleted; bufA/bufB alias dead tmp (ws 101->69MB).

#define NUSERS 100000
#define NITEMS 50000
#define NTOT   150000
#define DIM    64
#define NNZ_E  4800000

#define RPB     256    // rows per bucket
#define RSH     8
#define NBUCK   586    // ceil(150000/256)
#define CHUNK_E 8192
#define NPART   ((NNZ_E + CHUNK_E - 1) / CHUNK_E) // 586
#define NCB     37     // column bands of 4096 cols (150000>>12 = 36)
#define CSH     12
#define NBIN    (RPB * NCB)    // 9472: (rl, cb)
#define NOCT    (NBUCK * 64)   // 37,504 og (4 rows each); NOCT*4 = 150,016
#define FINCAP  6400000        // padded edge capacity (E ~ 5.73M, +867 sd slack)

__device__ __forceinline__ unsigned short benc(float f) {
    union { float f; unsigned u; } t; t.f = f;
    unsigned r = t.u + 0x7FFFu + ((t.u >> 16) & 1u);   // RNE
    return (unsigned short)(r >> 16);
}
__device__ __forceinline__ float blo(unsigned g) { return __uint_as_float(g << 16); }
__device__ __forceinline__ float bhi(unsigned g) { return __uint_as_float(g & 0xFFFF0000u); }

// ---- Fused Pass A: per-chunk hist + local scan + LDS bucket-sort + sequential
// writeback (amp 1.0). Writes cntmat[p][b], segoff[p][b], tmp.
// tmp word: x = col | rl<<18 (rl 8 bits), y = fp32 val.
__global__ void __launch_bounds__(512)
partA2_kernel(const int* __restrict__ rows, const int* __restrict__ cols,
              const float* __restrict__ vals, int* __restrict__ cntmat,
              int* __restrict__ segoff, int2* __restrict__ tmp) {
    __shared__ int2 buf[CHUNK_E];          // 64 KB
    __shared__ int cnt[NBUCK];
    __shared__ int st[512];
    int p = blockIdx.x;
    int c0 = p * CHUNK_E;
    int c1 = c0 + CHUNK_E; if (c1 > NNZ_E) c1 = NNZ_E;
    int nb = c1 - c0;
    int tid = threadIdx.x;
    for (int k = tid; k < NBUCK; k += 512) cnt[k] = 0;
    __syncthreads();
    int rloc[16];
#pragma unroll
    for (int u = 0; u < 16; ++u) {
        int e = c0 + tid + u * 512;
        rloc[u] = (e < c1) ? rows[e] : -1;
        if (rloc[u] >= 0) atomicAdd(&cnt[rloc[u] >> RSH], 1);
    }
    __syncthreads();
    int t0 = tid * 2;
    int cA = (t0     < NBUCK) ? cnt[t0]     : 0;
    int cB = (t0 + 1 < NBUCK) ? cnt[t0 + 1] : 0;
    int s = cA + cB;
    st[tid] = s;
    __syncthreads();
    for (int ofs = 1; ofs < 512; ofs <<= 1) {
        int a = (tid >= ofs) ? st[tid - ofs] : 0;
        __syncthreads();
        st[tid] += a;
        __syncthreads();
    }
    int P = st[tid] - s;
    if (t0 < NBUCK) {
        cnt[t0] = P;
        segoff[(size_t)p * NBUCK + t0] = P;
        cntmat[(size_t)p * NBUCK + t0] = cA;
    }
    if (t0 + 1 < NBUCK) {
        cnt[t0 + 1] = P + cA;
        segoff[(size_t)p * NBUCK + t0 + 1] = P + cA;
        cntmat[(size_t)p * NBUCK + t0 + 1] = cB;
    }
    __syncthreads();
#pragma unroll
    for (int u = 0; u < 16; ++u) {
        int e = c0 + tid + u * 512;
        if (rloc[u] >= 0) {
            int r = rloc[u];
            int b = r >> RSH, rl = r & (RPB - 1);
            int q = atomicAdd(&cnt[b], 1);
            buf[q] = make_int2(cols[e] | (rl << 18), __float_as_int(vals[e]));
        }
    }
    __syncthreads();
    for (int k = tid; k < nb; k += 512)
        tmp[c0 + k] = buf[k];              // fully sequential, coalesced
}

// ---- Per-bucket scan over chunks: runoffT[b][p] excl, [b][NPART] = total ----
__global__ void __launch_bounds__(1024)
colscan1_kernel(const int* __restrict__ cntmat, int* __restrict__ runoffT) {
    __shared__ int t[1024];
    int b = blockIdx.x;
    int tid = threadIdx.x;
    int v = (tid < NPART) ? cntmat[(size_t)tid * NBUCK + b] : 0;
    t[tid] = v;
    __syncthreads();
    for (int ofs = 1; ofs < 1024; ofs <<= 1) {
        int a = (tid >= ofs) ? t[tid - ofs] : 0;
        __syncthreads();
        t[tid] += a;
        __syncthreads();
    }
    if (tid < NPART) runoffT[(size_t)b * (NPART + 1) + tid] = t[tid] - v;
    if (tid == NPART - 1) runoffT[(size_t)b * (NPART + 1) + NPART] = t[tid];
}

// ---- Per-row degree histogram (global atomics, 150k spread -> low contention) ----
__global__ void __launch_bounds__(256)
degcnt_kernel(const int* __restrict__ rows, int* __restrict__ deg) {
    int i = blockIdx.x * 256 + threadIdx.x;
    int stride = gridDim.x * 256;
    for (; i < NNZ_E; i += stride) atomicAdd(&deg[rows[i]], 1);
}

// ---- Per-og padded size: p4[og] = 4 * max(deg[og*4 .. og*4+3]) ----
__global__ void __launch_bounds__(256)
ogmax_kernel(const int* __restrict__ deg, int* __restrict__ p4) {
    int og = blockIdx.x * 256 + threadIdx.x;
    if (og >= NOCT) return;
    int4 d = ((const int4*)deg)[og];       // deg sized 150016 = NOCT*4, zeroed tail
    int m = max(max(d.x, d.y), max(d.z, d.w));
    p4[og] = 4 * m;
}

// ---- Single-block exclusive scan of p4[NOCT] -> ogptr[NOCT+1] ----
__global__ void __launch_bounds__(1024)
ogscan_kernel(const int* __restrict__ p4, int* __restrict__ ogptr) {
    __shared__ int st[1024];
    int tid = threadIdx.x;
    int base = tid * 37;                   // 1024*37 = 37888 >= NOCT
    int sum = 0;
#pragma unroll 4
    for (int u = 0; u < 37; ++u) {
        int og = base + u;
        if (og < NOCT) sum += p4[og];
    }
    st[tid] = sum;
    __syncthreads();
    for (int ofs = 1; ofs < 1024; ofs <<= 1) {
        int a = (tid >= ofs) ? st[tid - ofs] : 0;
        __syncthreads();
        st[tid] += a;
        __syncthreads();
    }
    int P = st[tid] - sum;
#pragma unroll 4
    for (int u = 0; u < 37; ++u) {
        int og = base + u;
        if (og < NOCT) { ogptr[og] = P; P += p4[og]; }
    }
    if (tid == 1023) ogptr[NOCT] = st[1023];
}

// ---- Fused Phase B: gather bucket segments; counting sort by (rl, cb);
// TRANSPOSED emission: dest = ogptr[og] + i*4 + k (i = within-row index).
// fin word: col[0:17] | zero[18:19] | val12[20:31]. Pads pre-zeroed by memset.
__global__ void __launch_bounds__(1024)
partBF_kernel(const int* __restrict__ runoffT, const int* __restrict__ segoff,
              const int2* __restrict__ tmp, const int* __restrict__ ogptr,
              unsigned* __restrict__ fin) {
    __shared__ int cnt[NBIN];              // 37.9 KB, count->base->cursor in place
    __shared__ int st[1024];
    __shared__ int runoff[NPART + 1];
    __shared__ int soff[NPART];
    __shared__ int rowbase[RPB];
    __shared__ int ogbase[64];
    int b = blockIdx.x;
    int tid = threadIdx.x;
    for (int k = tid; k < NBIN; k += 1024) cnt[k] = 0;
    if (tid <= NPART) runoff[tid] = runoffT[(size_t)b * (NPART + 1) + tid];
    if (tid < NPART)  soff[tid]   = segoff[(size_t)tid * NBUCK + b];
    if (tid < 64)     ogbase[tid] = ogptr[b * 64 + tid];
    __syncthreads();
    int nb = runoff[NPART];
    // pass 1: histogram (rl, cb)
    for (int j = tid; j < nb; j += 1024) {
        int lo = 0, hi = NPART;
        while (hi - lo > 1) { int mid = (lo + hi) >> 1; if (runoff[mid] <= j) lo = mid; else hi = mid; }
        int src = lo * CHUNK_E + soff[lo] + (j - runoff[lo]);
        int x = tmp[src].x;
        int key = ((x >> 18) & 255) * NCB + ((x & 0x3FFFF) >> CSH);
        atomicAdd(&cnt[key], 1);
    }
    __syncthreads();
    // in-place exclusive scan of 9472 bins: 10/thread + block scan
    int t0 = tid * 10;
    int c[10];
    int s = 0;
#pragma unroll
    for (int u = 0; u < 10; ++u) {
        int idx = t0 + u;
        c[u] = (idx < NBIN) ? cnt[idx] : 0;
        s += c[u];
    }
    st[tid] = s;
    __syncthreads();
    for (int ofs = 1; ofs < 1024; ofs <<= 1) {
        int a = (tid >= ofs) ? st[tid - ofs] : 0;
        __syncthreads();
        st[tid] += a;
        __syncthreads();
    }
    int P = st[tid] - s;
#pragma unroll
    for (int u = 0; u < 10; ++u) {
        int idx = t0 + u;
        if (idx < NBIN) { cnt[idx] = P; P += c[u]; }
    }
    __syncthreads();
    if (tid < RPB) rowbase[tid] = cnt[tid * NCB];   // snapshot row starts
    __syncthreads();
    // pass 2: gather again (L2-hot), transposed scatter to fin
    for (int j = tid; j < nb; j += 1024) {
        int lo = 0, hi = NPART;
        while (hi - lo > 1) { int mid = (lo + hi) >> 1; if (runoff[mid] <= j) lo = mid; else hi = mid; }
        int src = lo * CHUNK_E + soff[lo] + (j - runoff[lo]);
        int2 t = tmp[src];
        int x = t.x;
        int rl = (x >> 18) & 255;
        int key = rl * NCB + ((x & 0x3FFFF) >> CSH);
        int q = atomicAdd(&cnt[key], 1);
        int i = q - rowbase[rl];                    // within-row index (cb-sorted)
        int dest = ogbase[rl >> 2] + i * 4 + (rl & 3);
        unsigned qq = (unsigned)__float2int_rn(__int_as_float(t.y) * 4096.f);
        if (qq > 4095u) qq = 4095u;
        fin[dest] = ((unsigned)x & 0x3FFFFu) | (qq << 20);
    }
}

// ---- x0h bf16-packed: uint j of row r = comps (2j, 2j+1) ----
__global__ void convert_kernel(const float2* __restrict__ user, const float2* __restrict__ item,
                               unsigned* __restrict__ xh2) {
    int i = blockIdx.x * blockDim.x + threadIdx.x;   // = row*32 + j
    if (i >= NTOT * 32) return;
    float2 v = (i < NUSERS * 32) ? user[i] : item[i - NUSERS * 32];
    xh2[i] = (unsigned)benc(v.x) | ((unsigned)benc(v.y) << 16);
}

// ---- SpMM: og=4 rows/oct, STATIC routing via transposed layout; uint4 edge
// loads (4 edges/load); 8 useful FMAs/edge; all blocks resident (sweep in phase).
__global__ void __launch_bounds__(256, 5)
spmm5_kernel(const int* __restrict__ ogptr, const unsigned* __restrict__ ed,
             const uint4* __restrict__ xin, uint4* __restrict__ yout,
             const float4* __restrict__ user, const float4* __restrict__ item,
             const uint4* __restrict__ y1, float4* __restrict__ out, int last) {
    int wid  = blockIdx.x * 4 + (threadIdx.x >> 6);
    int lane = threadIdx.x & 63;
    int g    = wid * 8 + (lane >> 3);          // og id, < NOCT
    int s    = lane & 7;
    int i0   = ogptr[g];
    int nt   = (ogptr[g + 1] - i0) >> 2;       // slots are groups of 4 edges
    const uint4* eq = (const uint4*)(ed + i0); // i0 % 4 == 0 by construction
    const float SCL = 1.f / 4096.f;
    float4 A00 = {0,0,0,0}, A01 = {0,0,0,0};
    float4 A10 = {0,0,0,0}, A11 = {0,0,0,0};
    float4 A20 = {0,0,0,0}, A21 = {0,0,0,0};
    float4 A30 = {0,0,0,0}, A31 = {0,0,0,0};

#define ACC(AK0, AK1, E, G) do { \
        float v = (float)((E) >> 20) * SCL; \
        AK0.x += v * blo((G).x); AK0.y += v * bhi((G).x); \
        AK0.z += v * blo((G).y); AK0.w += v * bhi((G).y); \
        AK1.x += v * blo((G).z); AK1.y += v * bhi((G).z); \
        AK1.z += v * blo((G).w); AK1.w += v * bhi((G).w); \
    } while (0)

    int ii = 0;
    for (; ii + 2 <= nt; ii += 2) {
        uint4 Ea = eq[ii], Eb = eq[ii + 1];
        uint4 G0 = xin[(size_t)(Ea.x & 0x3FFFFu) * 8 + s];
        uint4 G1 = xin[(size_t)(Ea.y & 0x3FFFFu) * 8 + s];
        uint4 G2 = xin[(size_t)(Ea.z & 0x3FFFFu) * 8 + s];
        uint4 G3 = xin[(size_t)(Ea.w & 0x3FFFFu) * 8 + s];
        uint4 G4 = xin[(size_t)(Eb.x & 0x3FFFFu) * 8 + s];
        uint4 G5 = xin[(size_t)(Eb.y & 0x3FFFFu) * 8 + s];
        uint4 G6 = xin[(size_t)(Eb.z & 0x3FFFFu) * 8 + s];
        uint4 G7 = xin[(size_t)(Eb.w & 0x3FFFFu) * 8 + s];
        ACC(A00, A01, Ea.x, G0); ACC(A10, A11, Ea.y, G1);
        ACC(A20, A21, Ea.z, G2); ACC(A30, A31, Ea.w, G3);
        ACC(A00, A01, Eb.x, G4); ACC(A10, A11, Eb.y, G5);
        ACC(A20, A21, Eb.z, G6); ACC(A30, A31, Eb.w, G7);
    }
    if (ii < nt) {
        uint4 Ea = eq[ii];
        uint4 G0 = xin[(size_t)(Ea.x & 0x3FFFFu) * 8 + s];
        uint4 G1 = xin[(size_t)(Ea.y & 0x3FFFFu) * 8 + s];
        uint4 G2 = xin[(size_t)(Ea.z & 0x3FFFFu) * 8 + s];
        uint4 G3 = xin[(size_t)(Ea.w & 0x3FFFFu) * 8 + s];
        ACC(A00, A01, Ea.x, G0); ACC(A10, A11, Ea.y, G1);
        ACC(A20, A21, Ea.z, G2); ACC(A30, A31, Ea.w, G3);
    }
#undef ACC

    if (!last) {
#define EPI(K, AK0, AK1) do { \
        int r = g * 4 + (K); \
        if (r < NTOT) { \
            uint4 o; \
            o.x = (unsigned)benc(AK0.x) | ((unsigned)benc(AK0.y) << 16); \
            o.y = (unsigned)benc(AK0.z) | ((unsigned)benc(AK0.w) << 16); \
            o.z = (unsigned)benc(AK1.x) | ((unsigned)benc(AK1.y) << 16); \
            o.w = (unsigned)benc(AK1.z) | ((unsigned)benc(AK1.w) << 16); \
            yout[(size_t)r * 8 + s] = o; \
        } \
    } while (0)
        EPI(0, A00, A01); EPI(1, A10, A11); EPI(2, A20, A21); EPI(3, A30, A31);
#undef EPI
    } else {
#define EPI(K, AK0, AK1) do { \
        int r = g * 4 + (K); \
        if (r < NTOT) { \
            size_t f4 = (size_t)r * 16 + 2 * s; \
            float4 x0a = (r < NUSERS) ? user[f4]     : item[f4     - (size_t)NUSERS * 16]; \
            float4 x0b = (r < NUSERS) ? user[f4 + 1] : item[f4 + 1 - (size_t)NUSERS * 16]; \
            uint4 u1 = y1[(size_t)r * 8 + s]; \
            uint4 u2 = xin[(size_t)r * 8 + s]; \
            float4 oa, ob; \
            oa.x = 0.25f * (x0a.x + blo(u1.x) + blo(u2.x) + AK0.x); \
            oa.y = 0.25f * (x0a.y + bhi(u1.x) + bhi(u2.x) + AK0.y); \
            oa.z = 0.25f * (x0a.z + blo(u1.y) + blo(u2.y) + AK0.z); \
            oa.w = 0.25f * (x0a.w + bhi(u1.y) + bhi(u2.y) + AK0.w); \
            ob.x = 0.25f * (x0b.x + blo(u1.z) + blo(u2.z) + AK1.x); \
            ob.y = 0.25f * (x0b.y + bhi(u1.z) + bhi(u2.z) + AK1.y); \
            ob.z = 0.25f * (x0b.z + blo(u1.w) + blo(u2.w) + AK1.z); \
            ob.w = 0.25f * (x0b.w + bhi(u1.w) + bhi(u2.w) + AK1.w); \
            out[f4]     = oa; \
            out[f4 + 1] = ob; \
        } \
    } while (0)
        EPI(0, A00, A01); EPI(1, A10, A11); EPI(2, A20, A21); EPI(3, A30, A31);
#undef EPI
    }
}

extern "C" void kernel_launch(void* const* d_in, const int* in_sizes, int n_in,
                              void* d_out, int out_size, void* d_ws, size_t ws_size,
                              hipStream_t stream) {
    const float* user = (const float*)d_in[0];
    const float* item = (const float*)d_in[1];
    const float* vals = (const float*)d_in[2];
    const int*   rows = (const int*)d_in[3];
    const int*   cols = (const int*)d_in[4];
    float* out = (float*)d_out;

    // ws layout (~69 MB): fin 25.6M | cntmat 1.37M | runoffT 1.38M | segoff 1.37M |
    // deg 600K | p4 150K | ogptr 150K | X 38.4M (tmp until partBF; then bufA|bufB)
    char* w = (char*)d_ws;
    unsigned* fin     = (unsigned*)w; w += (size_t)FINCAP * 4;
    int*      cntmat  = (int*)w;      w += (size_t)NPART * NBUCK * 4;
    int*      runoffT = (int*)w;      w += (size_t)NBUCK * (NPART + 1) * 4;
    int*      segoff  = (int*)w;      w += (size_t)NPART * NBUCK * 4;
    int*      deg     = (int*)w;      w += (size_t)(NOCT * 4) * 4;   // 150016, zeroed
    int*      p4      = (int*)w;      w += (size_t)NOCT * 4;
    int*      ogptr   = (int*)w;      w += (size_t)(NOCT + 1) * 4;
    char*     X       = w;
    int2*     tmp     = (int2*)X;                                    // 38.4 MB
    unsigned* bufA    = (unsigned*)X;                                // after partBF
    unsigned* bufB    = (unsigned*)(X + (size_t)NTOT * DIM * 2);

    const int blk = 256;
    const int gConv = (NTOT * 32 + blk - 1) / blk;       // 18750
    const int gSpmm = NOCT / 32;                         // 1172 (4 waves, 8 ogs/wave)

    hipMemsetAsync(deg, 0, (size_t)(NOCT * 4) * 4, stream);
    hipMemsetAsync(fin, 0, (size_t)FINCAP * 4, stream);  // pads = {col 0, val 0}

    partA2_kernel<<<NPART, 512, 0, stream>>>(rows, cols, vals, cntmat, segoff, tmp);
    colscan1_kernel<<<NBUCK, 1024, 0, stream>>>(cntmat, runoffT);
    degcnt_kernel<<<1024, 256, 0, stream>>>(rows, deg);
    ogmax_kernel<<<(NOCT + 255) / 256, 256, 0, stream>>>(deg, p4);
    ogscan_kernel<<<1, 1024, 0, stream>>>(p4, ogptr);
    partBF_kernel<<<NBUCK, 1024, 0, stream>>>(runoffT, segoff, tmp, ogptr, fin);

    convert_kernel<<<gConv, blk, 0, stream>>>((const float2*)user, (const float2*)item, bufA);

    spmm5_kernel<<<gSpmm, blk, 0, stream>>>(ogptr, fin, (const uint4*)bufA, (uint4*)bufB,
                                            (const float4*)user, (const float4*)item,
                                            (const uint4*)bufB, (float4*)out, 0); // y1=bufB
    spmm5_kernel<<<gSpmm, blk, 0, stream>>>(ogptr, fin, (const uint4*)bufB, (uint4*)bufA,
                                            (const float4*)user, (const float4*)item,
                                            (const uint4*)bufB, (float4*)out, 0); // y2=bufA
    spmm5_kernel<<<gSpmm, blk, 0, stream>>>(ogptr, fin, (const uint4*)bufA, (uint4*)bufA,
                                            (const float4*)user, (const float4*)item,
                                            (const uint4*)bufB, (float4*)out, 1); // fused mean
}

// Round 8
// 466.400 us; speedup vs baseline: 1.8141x; 1.8141x over previous
//
#include <hip/hip_runtime.h>

// LightGCN on MI355X (gfx950). Round 16 — consolidation of proven parts.
// R15 post-mortem: (1) degcnt's 4.8M scattered GLOBAL atomics = 186us (149MB
// line-granular RFO — same physics as R12's scatter amp; global atomics are NOT
// cheap when scattered). (2) transpose-pad spmm lost the JOINT cb-sort: each
// row swept its own quantile ladder, degree CV ~18% spread the 4 rows' progress
// by MBs -> locality gone (+60us/layer). Lesson: R13's locality came from the
// joint per-og cb-sorted stream, not merely residency.
// R16 = R13 verbatim (partBF, optr, spmm4) + R14's fused partA2 (60->35us,
// amp-1.0 sequential writeback) + layer-3 epilogue reads x0 from bf16 x0h
// (saves 19.2MB L3 fetch vs fp32 user/item). bufB/bufC alias dead tmp.
// R13 evidence: spmm4 is FETCH-bound (239MB/3.2TB/s=75us vs VALU 48us), so
// VALU-waste chasing (R14/R15) attacked the wrong pipe.

#define NUSERS 100000
#define NITEMS 50000
#define NTOT   150000
#define DIM    64
#define NNZ_E  4800000

#define RPB     256    // rows per bucket
#define RSH     8
#define NBUCK   586    // ceil(150000/256)
#define CHUNK_E 8192
#define NPART   ((NNZ_E + CHUNK_E - 1) / CHUNK_E) // 586
#define NCB     74     // column bands of 2048 cols (150000>>11 = 73)
#define CSH     11
#define NBIN    (64 * NCB)     // 4736: og x cb
#define NOCT    (NBUCK * 64)   // 37,504 og (4 rows each)

__device__ __forceinline__ unsigned short benc(float f) {
    union { float f; unsigned u; } t; t.f = f;
    unsigned r = t.u + 0x7FFFu + ((t.u >> 16) & 1u);   // RNE
    return (unsigned short)(r >> 16);
}
__device__ __forceinline__ float blo(unsigned g) { return __uint_as_float(g << 16); }
__device__ __forceinline__ float bhi(unsigned g) { return __uint_as_float(g & 0xFFFF0000u); }

// ---- Fused Pass A: per-chunk hist + local scan + LDS bucket-sort + sequential
// writeback (amp 1.0). Writes cntmat[p][b], segoff[p][b], tmp.
// tmp word: x = col | rl<<18 (rl 8 bits), y = fp32 val.
__global__ void __launch_bounds__(512)
partA2_kernel(const int* __restrict__ rows, const int* __restrict__ cols,
              const float* __restrict__ vals, int* __restrict__ cntmat,
              int* __restrict__ segoff, int2* __restrict__ tmp) {
    __shared__ int2 buf[CHUNK_E];          // 64 KB
    __shared__ int cnt[NBUCK];
    __shared__ int st[512];
    int p = blockIdx.x;
    int c0 = p * CHUNK_E;
    int c1 = c0 + CHUNK_E; if (c1 > NNZ_E) c1 = NNZ_E;
    int nb = c1 - c0;
    int tid = threadIdx.x;
    for (int k = tid; k < NBUCK; k += 512) cnt[k] = 0;
    __syncthreads();
    int rloc[16];
#pragma unroll
    for (int u = 0; u < 16; ++u) {
        int e = c0 + tid + u * 512;
        rloc[u] = (e < c1) ? rows[e] : -1;
        if (rloc[u] >= 0) atomicAdd(&cnt[rloc[u] >> RSH], 1);
    }
    __syncthreads();
    int t0 = tid * 2;
    int cA = (t0     < NBUCK) ? cnt[t0]     : 0;
    int cB = (t0 + 1 < NBUCK) ? cnt[t0 + 1] : 0;
    int s = cA + cB;
    st[tid] = s;
    __syncthreads();
    for (int ofs = 1; ofs < 512; ofs <<= 1) {
        int a = (tid >= ofs) ? st[tid - ofs] : 0;
        __syncthreads();
        st[tid] += a;
        __syncthreads();
    }
    int P = st[tid] - s;
    if (t0 < NBUCK) {
        cnt[t0] = P;
        segoff[(size_t)p * NBUCK + t0] = P;
        cntmat[(size_t)p * NBUCK + t0] = cA;
    }
    if (t0 + 1 < NBUCK) {
        cnt[t0 + 1] = P + cA;
        segoff[(size_t)p * NBUCK + t0 + 1] = P + cA;
        cntmat[(size_t)p * NBUCK + t0 + 1] = cB;
    }
    __syncthreads();
#pragma unroll
    for (int u = 0; u < 16; ++u) {
        int e = c0 + tid + u * 512;
        if (rloc[u] >= 0) {
            int r = rloc[u];
            int b = r >> RSH, rl = r & (RPB - 1);
            int q = atomicAdd(&cnt[b], 1);
            buf[q] = make_int2(cols[e] | (rl << 18), __float_as_int(vals[e]));
        }
    }
    __syncthreads();
    for (int k = tid; k < nb; k += 512)
        tmp[c0 + k] = buf[k];              // fully sequential, coalesced
}

// ---- Per-bucket scan over chunks: runoffT[b][p] excl, [b][NPART] = total ----
__global__ void __launch_bounds__(1024)
colscan1_kernel(const int* __restrict__ cntmat, int* __restrict__ runoffT,
                int* __restrict__ colTotal) {
    __shared__ int t[1024];
    int b = blockIdx.x;
    int tid = threadIdx.x;
    int v = (tid < NPART) ? cntmat[(size_t)tid * NBUCK + b] : 0;
    t[tid] = v;
    __syncthreads();
    for (int ofs = 1; ofs < 1024; ofs <<= 1) {
        int a = (tid >= ofs) ? t[tid - ofs] : 0;
        __syncthreads();
        t[tid] += a;
        __syncthreads();
    }
    if (tid < NPART) runoffT[(size_t)b * (NPART + 1) + tid] = t[tid] - v;
    if (tid == NPART - 1) {
        runoffT[(size_t)b * (NPART + 1) + NPART] = t[tid];
        colTotal[b] = t[tid];
    }
}

// ---- Exclusive scan of colTotal (NBUCK=586) -> bptr[NBUCK+1] ----
__global__ void __launch_bounds__(1024)
colscan2_kernel(const int* __restrict__ colTotal, int* __restrict__ bptr) {
    __shared__ int t[1024];
    int tid = threadIdx.x;
    int v = (tid < NBUCK) ? colTotal[tid] : 0;
    t[tid] = v;
    __syncthreads();
    for (int ofs = 1; ofs < 1024; ofs <<= 1) {
        int a = (tid >= ofs) ? t[tid - ofs] : 0;
        __syncthreads();
        t[tid] += a;
        __syncthreads();
    }
    if (tid < NBUCK) bptr[tid] = t[tid] - v;
    if (tid == 1023) bptr[NBUCK] = t[1023];
}

// ---- Fused Phase B: gather bucket segments; counting sort by (og, col>>11) ----
// fin word: col[0:17] | k=rl&3 [18:19] | val12 [20:31]. Writes optr[og CSR].
__global__ void __launch_bounds__(1024)
partBF_kernel(const int* __restrict__ bptr, const int* __restrict__ runoffT,
              const int* __restrict__ segoff, const int2* __restrict__ tmp,
              unsigned* __restrict__ fin, int* __restrict__ optr) {
    __shared__ int cnt[NBIN];
    __shared__ int base[NBIN];
    __shared__ int st[1024];
    __shared__ int runoff[NPART + 1];
    __shared__ int soff[NPART];
    int b = blockIdx.x;
    int bb0 = bptr[b];
    int tid = threadIdx.x;
    for (int k = tid; k < NBIN; k += 1024) cnt[k] = 0;
    if (tid <= NPART) runoff[tid] = runoffT[(size_t)b * (NPART + 1) + tid];
    if (tid < NPART)  soff[tid]   = segoff[(size_t)tid * NBUCK + b];
    __syncthreads();
    int nb = runoff[NPART];
    // pass 1: histogram composite keys
    for (int j = tid; j < nb; j += 1024) {
        int lo = 0, hi = NPART;
        while (hi - lo > 1) { int mid = (lo + hi) >> 1; if (runoff[mid] <= j) lo = mid; else hi = mid; }
        int src = lo * CHUNK_E + soff[lo] + (j - runoff[lo]);
        int x = tmp[src].x;
        int key = ((x >> 20) & 63) * NCB + ((x & 0x3FFFF) >> CSH);
        atomicAdd(&cnt[key], 1);
    }
    __syncthreads();
    // exclusive scan of 4736 bins: 5 bins/thread + block scan
    int t0 = tid * 5;
    int c0 = (t0     < NBIN) ? cnt[t0]     : 0;
    int c1 = (t0 + 1 < NBIN) ? cnt[t0 + 1] : 0;
    int c2 = (t0 + 2 < NBIN) ? cnt[t0 + 2] : 0;
    int c3 = (t0 + 3 < NBIN) ? cnt[t0 + 3] : 0;
    int c4 = (t0 + 4 < NBIN) ? cnt[t0 + 4] : 0;
    int s = c0 + c1 + c2 + c3 + c4;
    st[tid] = s;
    __syncthreads();
    for (int ofs = 1; ofs < 1024; ofs <<= 1) {
        int a = (tid >= ofs) ? st[tid - ofs] : 0;
        __syncthreads();
        st[tid] += a;
        __syncthreads();
    }
    int P = st[tid] - s;
    if (t0     < NBIN) base[t0]     = P;
    if (t0 + 1 < NBIN) base[t0 + 1] = P + c0;
    if (t0 + 2 < NBIN) base[t0 + 2] = P + c0 + c1;
    if (t0 + 3 < NBIN) base[t0 + 3] = P + c0 + c1 + c2;
    if (t0 + 4 < NBIN) base[t0 + 4] = P + c0 + c1 + c2 + c3;
    __syncthreads();
    if (tid < 64) optr[b * 64 + tid] = bb0 + base[tid * NCB];
    if (b == NBUCK - 1 && tid == 0) optr[NBUCK * 64] = bb0 + nb;
    __syncthreads();   // optr snapshot of base before scatter mutates it
    // pass 2: gather again (L2-hot), scatter to fin (4B, quantized val)
    for (int j = tid; j < nb; j += 1024) {
        int lo = 0, hi = NPART;
        while (hi - lo > 1) { int mid = (lo + hi) >> 1; if (runoff[mid] <= j) lo = mid; else hi = mid; }
        int src = lo * CHUNK_E + soff[lo] + (j - runoff[lo]);
        int2 t = tmp[src];
        int x = t.x;
        int key = ((x >> 20) & 63) * NCB + ((x & 0x3FFFF) >> CSH);
        int q = atomicAdd(&base[key], 1);
        unsigned qq = (unsigned)__float2int_rn(__int_as_float(t.y) * 4096.f);
        if (qq > 4095u) qq = 4095u;
        fin[bb0 + q] = ((unsigned)x & 0xFFFFFu) | (qq << 20);
    }
}

// ---- x0h bf16-packed: uint j of row r = comps (2j, 2j+1) ----
__global__ void convert_kernel(const float2* __restrict__ user, const float2* __restrict__ item,
                               unsigned* __restrict__ xh2) {
    int i = blockIdx.x * blockDim.x + threadIdx.x;   // = row*32 + j
    if (i >= NTOT * 32) return;
    float2 v = (i < NUSERS * 32) ? user[i] : item[i - NUSERS * 32];
    xh2[i] = (unsigned)benc(v.x) | ((unsigned)benc(v.y) << 16);
}

// ---- SpMM: 8-lane oct owns 4 rows; register acc; 4B cb-band-sorted edges.
// Layer-3 epilogue reads x0 from bf16 x0h (not fp32 user/item): -19.2MB fetch.
__global__ void __launch_bounds__(256)
spmm4_kernel(const int* __restrict__ optr, const unsigned* __restrict__ ed,
             const uint4* __restrict__ xin, uint4* __restrict__ yout,
             const uint4* __restrict__ x0h, const uint4* __restrict__ y1,
             float4* __restrict__ out, int last) {
    int wid  = blockIdx.x * 4 + (threadIdx.x >> 6);
    int lane = threadIdx.x & 63;
    int g    = wid * 8 + (lane >> 3);          // og id, < NOCT
    int s    = lane & 7;
    int i    = optr[g];
    int end  = optr[g + 1];
    const float SCL = 1.f / 4096.f;
    float4 A00 = {0,0,0,0}, A01 = {0,0,0,0};
    float4 A10 = {0,0,0,0}, A11 = {0,0,0,0};
    float4 A20 = {0,0,0,0}, A21 = {0,0,0,0};
    float4 A30 = {0,0,0,0}, A31 = {0,0,0,0};

#define PROC(E, G) do { \
        float v  = (float)((E) >> 20) * SCL; \
        int   k  = ((E) >> 18) & 3; \
        float s0 = (k == 0) ? v : 0.f, s1 = (k == 1) ? v : 0.f; \
        float s2 = (k == 2) ? v : 0.f, s3 = (k == 3) ? v : 0.f; \
        float f0 = blo((G).x), f1 = bhi((G).x), f2 = blo((G).y), f3 = bhi((G).y); \
        float f4_ = blo((G).z), f5 = bhi((G).z), f6 = blo((G).w), f7 = bhi((G).w); \
        A00.x += s0*f0; A00.y += s0*f1; A00.z += s0*f2; A00.w += s0*f3; \
        A01.x += s0*f4_; A01.y += s0*f5; A01.z += s0*f6; A01.w += s0*f7; \
        A10.x += s1*f0; A10.y += s1*f1; A10.z += s1*f2; A10.w += s1*f3; \
        A11.x += s1*f4_; A11.y += s1*f5; A11.z += s1*f6; A11.w += s1*f7; \
        A20.x += s2*f0; A20.y += s2*f1; A20.z += s2*f2; A20.w += s2*f3; \
        A21.x += s2*f4_; A21.y += s2*f5; A21.z += s2*f6; A21.w += s2*f7; \
        A30.x += s3*f0; A30.y += s3*f1; A30.z += s3*f2; A30.w += s3*f3; \
        A31.x += s3*f4_; A31.y += s3*f5; A31.z += s3*f6; A31.w += s3*f7; \
    } while (0)

    for (; i + 4 <= end; i += 4) {
        unsigned e0 = ed[i], e1 = ed[i + 1], e2 = ed[i + 2], e3 = ed[i + 3];
        uint4 g0 = xin[(size_t)(e0 & 0x3FFFF) * 8 + s];
        uint4 g1 = xin[(size_t)(e1 & 0x3FFFF) * 8 + s];
        uint4 g2 = xin[(size_t)(e2 & 0x3FFFF) * 8 + s];
        uint4 g3 = xin[(size_t)(e3 & 0x3FFFF) * 8 + s];
        PROC(e0, g0); PROC(e1, g1); PROC(e2, g2); PROC(e3, g3);
    }
    for (; i < end; ++i) {
        unsigned e = ed[i];
        uint4 gg = xin[(size_t)(e & 0x3FFFF) * 8 + s];
        PROC(e, gg);
    }
#undef PROC

    if (!last) {
#define EPI(K, AK0, AK1) do { \
        int r = g * 4 + (K); \
        if (r < NTOT) { \
            uint4 o; \
            o.x = (unsigned)benc(AK0.x) | ((unsigned)benc(AK0.y) << 16); \
            o.y = (unsigned)benc(AK0.z) | ((unsigned)benc(AK0.w) << 16); \
            o.z = (unsigned)benc(AK1.x) | ((unsigned)benc(AK1.y) << 16); \
            o.w = (unsigned)benc(AK1.z) | ((unsigned)benc(AK1.w) << 16); \
            yout[(size_t)r * 8 + s] = o; \
        } \
    } while (0)
        EPI(0, A00, A01); EPI(1, A10, A11); EPI(2, A20, A21); EPI(3, A30, A31);
#undef EPI
    } else {
#define EPI(K, AK0, AK1) do { \
        int r = g * 4 + (K); \
        if (r < NTOT) { \
            uint4 u0 = x0h[(size_t)r * 8 + s]; \
            uint4 u1 = y1[(size_t)r * 8 + s]; \
            uint4 u2 = xin[(size_t)r * 8 + s]; \
            size_t f4 = (size_t)r * 16 + 2 * s; \
            float4 oa, ob; \
            oa.x = 0.25f * (blo(u0.x) + blo(u1.x) + blo(u2.x) + AK0.x); \
            oa.y = 0.25f * (bhi(u0.x) + bhi(u1.x) + bhi(u2.x) + AK0.y); \
            oa.z = 0.25f * (blo(u0.y) + blo(u1.y) + blo(u2.y) + AK0.z); \
            oa.w = 0.25f * (bhi(u0.y) + bhi(u1.y) + bhi(u2.y) + AK0.w); \
            ob.x = 0.25f * (blo(u0.z) + blo(u1.z) + blo(u2.z) + AK1.x); \
            ob.y = 0.25f * (bhi(u0.z) + bhi(u1.z) + bhi(u2.z) + AK1.y); \
            ob.z = 0.25f * (blo(u0.w) + blo(u1.w) + blo(u2.w) + AK1.z); \
            ob.w = 0.25f * (bhi(u0.w) + bhi(u1.w) + bhi(u2.w) + AK1.w); \
            out[f4]     = oa; \
            out[f4 + 1] = ob; \
        } \
    } while (0)
        EPI(0, A00, A01); EPI(1, A10, A11); EPI(2, A20, A21); EPI(3, A30, A31);
#undef EPI
    }
}

extern "C" void kernel_launch(void* const* d_in, const int* in_sizes, int n_in,
                              void* d_out, int out_size, void* d_ws, size_t ws_size,
                              hipStream_t stream) {
    const float* user = (const float*)d_in[0];
    const float* item = (const float*)d_in[1];
    const float* vals = (const float*)d_in[2];
    const int*   rows = (const int*)d_in[3];
    const int*   cols = (const int*)d_in[4];
    float* out = (float*)d_out;

    // ws layout (~81 MB): X 38.4M (tmp until partBF; then bufB|bufC) | fin 19.2M |
    // bufX 19.2M | cntmat 1.37M | runoffT 1.38M | segoff 1.37M | optr 150K |
    // colTotal | bptr
    char* w = (char*)d_ws;
    char*     X        = w;            w += (size_t)NNZ_E * 8;
    unsigned* fin      = (unsigned*)w; w += (size_t)NNZ_E * 4;
    unsigned* bufX     = (unsigned*)w; w += (size_t)NTOT * DIM * 2;   // x0h, persistent
    int*      cntmat   = (int*)w;      w += (size_t)NPART * NBUCK * 4;
    int*      runoffT  = (int*)w;      w += (size_t)NBUCK * (NPART + 1) * 4;
    int*      segoff   = (int*)w;      w += (size_t)NPART * NBUCK * 4;
    int*      optr     = (int*)w;      w += (size_t)(NOCT + 1) * 4;
    int*      colTotal = (int*)w;      w += (size_t)NBUCK * 4;
    int*      bptr     = (int*)w;

    int2*     tmp  = (int2*)X;                                  // dead after partBF
    unsigned* bufB = (unsigned*)X;                              // y1h
    unsigned* bufC = (unsigned*)(X + (size_t)NTOT * DIM * 2);   // y2h

    const int blk = 256;
    const int gConv = (NTOT * 32 + blk - 1) / blk;       // 18750
    const int gSpmm = NOCT / 32;                         // 1172 (4 waves, 8 ogs/wave)

    partA2_kernel<<<NPART, 512, 0, stream>>>(rows, cols, vals, cntmat, segoff, tmp);
    colscan1_kernel<<<NBUCK, 1024, 0, stream>>>(cntmat, runoffT, colTotal);
    colscan2_kernel<<<1, 1024, 0, stream>>>(colTotal, bptr);
    partBF_kernel<<<NBUCK, 1024, 0, stream>>>(bptr, runoffT, segoff, tmp, fin, optr);

    convert_kernel<<<gConv, blk, 0, stream>>>((const float2*)user, (const float2*)item, bufX);

    // tmp dead from here; bufB/bufC occupy its space.
    spmm4_kernel<<<gSpmm, blk, 0, stream>>>(optr, fin, (const uint4*)bufX, (uint4*)bufB,
                                            (const uint4*)bufX, (const uint4*)bufB,
                                            (float4*)out, 0);   // y1 = bufB
    spmm4_kernel<<<gSpmm, blk, 0, stream>>>(optr, fin, (const uint4*)bufB, (uint4*)bufC,
                                            (const uint4*)bufX, (const uint4*)bufB,
                                            (float4*)out, 0);   // y2 = bufC
    spmm4_kernel<<<gSpmm, blk, 0, stream>>>(optr, fin, (const uint4*)bufC, (uint4*)bufC,
                                            (const uint4*)bufX, (const uint4*)bufB,
                                            (float4*)out, 1);   // fused mean -> out
}

// Round 9
// 461.704 us; speedup vs baseline: 1.8326x; 1.0102x over previous
//
#include <hip/hip_runtime.h>

// LightGCN on MI355X (gfx950). Round 17.
// R16 = 466us best. Cross-round evidence: spmm dur == FETCH/2.6-3.2TB/s in
// R13/R14/R16 => fetch-bound; VALU-cutting is pointless (R14 proved it), fetch
// floor ~(154 gather + 19.2 fin)/2.7 ~ 65us/layer. Budget says partBF ~80-85us
// (just under top-5): it binary-searches AND gathers tmp TWICE (2x38.4MB).
// R17 (safe edits only):
//  1) partBF caches the gathered int2 edges in registers during pass 1
//     (<=12/thread, static unroll - rule: no runtime-indexed reg arrays);
//     pass 2 = no search, no tmp re-read. Predict partBF -> ~55-60us.
//  2) spmm loads edges as uint4 (4 edges/load, alignment prologue): VMEM issue
//     8->5 per 4 edges. Predict spmm 86 -> 82-84, FETCH unchanged ~223MB.
// If spmm holds >=82us at same FETCH: fetch-bound confirmed; next lever is the
// XCD column-split + partials (gated on absmax headroom, currently 1 bf16 ulp).

#define NUSERS 100000
#define NITEMS 50000
#define NTOT   150000
#define DIM    64
#define NNZ_E  4800000

#define RPB     256    // rows per bucket
#define RSH     8
#define NBUCK   586    // ceil(150000/256)
#define CHUNK_E 8192
#define NPART   ((NNZ_E + CHUNK_E - 1) / CHUNK_E) // 586
#define NCB     74     // column bands of 2048 cols (150000>>11 = 73)
#define CSH     11
#define NBIN    (64 * NCB)     // 4736: og x cb
#define NOCT    (NBUCK * 64)   // 37,504 og (4 rows each)
#define EPT     12             // partBF cached edges/thread (max bucket ~8.5K/1024 = 9)

__device__ __forceinline__ unsigned short benc(float f) {
    union { float f; unsigned u; } t; t.f = f;
    unsigned r = t.u + 0x7FFFu + ((t.u >> 16) & 1u);   // RNE
    return (unsigned short)(r >> 16);
}
__device__ __forceinline__ float blo(unsigned g) { return __uint_as_float(g << 16); }
__device__ __forceinline__ float bhi(unsigned g) { return __uint_as_float(g & 0xFFFF0000u); }

// ---- Fused Pass A: per-chunk hist + local scan + LDS bucket-sort + sequential
// writeback (amp 1.0). Writes cntmat[p][b], segoff[p][b], tmp.
// tmp word: x = col | rl<<18 (rl 8 bits), y = fp32 val.
__global__ void __launch_bounds__(512)
partA2_kernel(const int* __restrict__ rows, const int* __restrict__ cols,
              const float* __restrict__ vals, int* __restrict__ cntmat,
              int* __restrict__ segoff, int2* __restrict__ tmp) {
    __shared__ int2 buf[CHUNK_E];          // 64 KB
    __shared__ int cnt[NBUCK];
    __shared__ int st[512];
    int p = blockIdx.x;
    int c0 = p * CHUNK_E;
    int c1 = c0 + CHUNK_E; if (c1 > NNZ_E) c1 = NNZ_E;
    int nb = c1 - c0;
    int tid = threadIdx.x;
    for (int k = tid; k < NBUCK; k += 512) cnt[k] = 0;
    __syncthreads();
    int rloc[16];
#pragma unroll
    for (int u = 0; u < 16; ++u) {
        int e = c0 + tid + u * 512;
        rloc[u] = (e < c1) ? rows[e] : -1;
        if (rloc[u] >= 0) atomicAdd(&cnt[rloc[u] >> RSH], 1);
    }
    __syncthreads();
    int t0 = tid * 2;
    int cA = (t0     < NBUCK) ? cnt[t0]     : 0;
    int cB = (t0 + 1 < NBUCK) ? cnt[t0 + 1] : 0;
    int s = cA + cB;
    st[tid] = s;
    __syncthreads();
    for (int ofs = 1; ofs < 512; ofs <<= 1) {
        int a = (tid >= ofs) ? st[tid - ofs] : 0;
        __syncthreads();
        st[tid] += a;
        __syncthreads();
    }
    int P = st[tid] - s;
    if (t0 < NBUCK) {
        cnt[t0] = P;
        segoff[(size_t)p * NBUCK + t0] = P;
        cntmat[(size_t)p * NBUCK + t0] = cA;
    }
    if (t0 + 1 < NBUCK) {
        cnt[t0 + 1] = P + cA;
        segoff[(size_t)p * NBUCK + t0 + 1] = P + cA;
        cntmat[(size_t)p * NBUCK + t0 + 1] = cB;
    }
    __syncthreads();
#pragma unroll
    for (int u = 0; u < 16; ++u) {
        int e = c0 + tid + u * 512;
        if (rloc[u] >= 0) {
            int r = rloc[u];
            int b = r >> RSH, rl = r & (RPB - 1);
            int q = atomicAdd(&cnt[b], 1);
            buf[q] = make_int2(cols[e] | (rl << 18), __float_as_int(vals[e]));
        }
    }
    __syncthreads();
    for (int k = tid; k < nb; k += 512)
        tmp[c0 + k] = buf[k];              // fully sequential, coalesced
}

// ---- Per-bucket scan over chunks: runoffT[b][p] excl, [b][NPART] = total ----
__global__ void __launch_bounds__(1024)
colscan1_kernel(const int* __restrict__ cntmat, int* __restrict__ runoffT,
                int* __restrict__ colTotal) {
    __shared__ int t[1024];
    int b = blockIdx.x;
    int tid = threadIdx.x;
    int v = (tid < NPART) ? cntmat[(size_t)tid * NBUCK + b] : 0;
    t[tid] = v;
    __syncthreads();
    for (int ofs = 1; ofs < 1024; ofs <<= 1) {
        int a = (tid >= ofs) ? t[tid - ofs] : 0;
        __syncthreads();
        t[tid] += a;
        __syncthreads();
    }
    if (tid < NPART) runoffT[(size_t)b * (NPART + 1) + tid] = t[tid] - v;
    if (tid == NPART - 1) {
        runoffT[(size_t)b * (NPART + 1) + NPART] = t[tid];
        colTotal[b] = t[tid];
    }
}

// ---- Exclusive scan of colTotal (NBUCK=586) -> bptr[NBUCK+1] ----
__global__ void __launch_bounds__(1024)
colscan2_kernel(const int* __restrict__ colTotal, int* __restrict__ bptr) {
    __shared__ int t[1024];
    int tid = threadIdx.x;
    int v = (tid < NBUCK) ? colTotal[tid] : 0;
    t[tid] = v;
    __syncthreads();
    for (int ofs = 1; ofs < 1024; ofs <<= 1) {
        int a = (tid >= ofs) ? t[tid - ofs] : 0;
        __syncthreads();
        t[tid] += a;
        __syncthreads();
    }
    if (tid < NBUCK) bptr[tid] = t[tid] - v;
    if (tid == 1023) bptr[NBUCK] = t[1023];
}

// ---- Fused Phase B: gather bucket segments ONCE (values cached in registers);
// counting sort by (og, col>>11). fin word: col[0:17]|k[18:19]|val12[20:31]. ----
__global__ void __launch_bounds__(1024)
partBF_kernel(const int* __restrict__ bptr, const int* __restrict__ runoffT,
              const int* __restrict__ segoff, const int2* __restrict__ tmp,
              unsigned* __restrict__ fin, int* __restrict__ optr) {
    __shared__ int cnt[NBIN];
    __shared__ int base[NBIN];
    __shared__ int st[1024];
    __shared__ int runoff[NPART + 1];
    __shared__ int soff[NPART];
    int b = blockIdx.x;
    int bb0 = bptr[b];
    int tid = threadIdx.x;
    for (int k = tid; k < NBIN; k += 1024) cnt[k] = 0;
    if (tid <= NPART) runoff[tid] = runoffT[(size_t)b * (NPART + 1) + tid];
    if (tid < NPART)  soff[tid]   = segoff[(size_t)tid * NBUCK + b];
    __syncthreads();
    int nb = runoff[NPART];
    // pass 1: gather + histogram; cache edge values in registers (static idx)
    int2 ev[EPT];
#pragma unroll
    for (int u = 0; u < EPT; ++u) {
        int j = tid + (u << 10);
        if (j < nb) {
            int lo = 0, hi = NPART;
            while (hi - lo > 1) { int mid = (lo + hi) >> 1; if (runoff[mid] <= j) lo = mid; else hi = mid; }
            int src = lo * CHUNK_E + soff[lo] + (j - runoff[lo]);
            int2 t = tmp[src];
            ev[u] = t;
            int key = ((t.x >> 20) & 63) * NCB + ((t.x & 0x3FFFF) >> CSH);
            atomicAdd(&cnt[key], 1);
        }
    }
    // overflow path (nb > EPT*1024): not expected for this data, kept for safety
    for (int j = tid + (EPT << 10); j < nb; j += 1024) {
        int lo = 0, hi = NPART;
        while (hi - lo > 1) { int mid = (lo + hi) >> 1; if (runoff[mid] <= j) lo = mid; else hi = mid; }
        int src = lo * CHUNK_E + soff[lo] + (j - runoff[lo]);
        int x = tmp[src].x;
        int key = ((x >> 20) & 63) * NCB + ((x & 0x3FFFF) >> CSH);
        atomicAdd(&cnt[key], 1);
    }
    __syncthreads();
    // exclusive scan of 4736 bins: 5 bins/thread + block scan
    int t0 = tid * 5;
    int c0 = (t0     < NBIN) ? cnt[t0]     : 0;
    int c1 = (t0 + 1 < NBIN) ? cnt[t0 + 1] : 0;
    int c2 = (t0 + 2 < NBIN) ? cnt[t0 + 2] : 0;
    int c3 = (t0 + 3 < NBIN) ? cnt[t0 + 3] : 0;
    int c4 = (t0 + 4 < NBIN) ? cnt[t0 + 4] : 0;
    int s = c0 + c1 + c2 + c3 + c4;
    st[tid] = s;
    __syncthreads();
    for (int ofs = 1; ofs < 1024; ofs <<= 1) {
        int a = (tid >= ofs) ? st[tid - ofs] : 0;
        __syncthreads();
        st[tid] += a;
        __syncthreads();
    }
    int P = st[tid] - s;
    if (t0     < NBIN) base[t0]     = P;
    if (t0 + 1 < NBIN) base[t0 + 1] = P + c0;
    if (t0 + 2 < NBIN) base[t0 + 2] = P + c0 + c1;
    if (t0 + 3 < NBIN) base[t0 + 3] = P + c0 + c1 + c2;
    if (t0 + 4 < NBIN) base[t0 + 4] = P + c0 + c1 + c2 + c3;
    __syncthreads();
    if (tid < 64) optr[b * 64 + tid] = bb0 + base[tid * NCB];
    if (b == NBUCK - 1 && tid == 0) optr[NBUCK * 64] = bb0 + nb;
    __syncthreads();   // optr snapshot of base before scatter mutates it
    // pass 2: scatter from registers (no search, no tmp re-read)
#pragma unroll
    for (int u = 0; u < EPT; ++u) {
        int j = tid + (u << 10);
        if (j < nb) {
            int2 t = ev[u];
            int key = ((t.x >> 20) & 63) * NCB + ((t.x & 0x3FFFF) >> CSH);
            int q = atomicAdd(&base[key], 1);
            unsigned qq = (unsigned)__float2int_rn(__int_as_float(t.y) * 4096.f);
            if (qq > 4095u) qq = 4095u;
            fin[bb0 + q] = ((unsigned)t.x & 0xFFFFFu) | (qq << 20);
        }
    }
    for (int j = tid + (EPT << 10); j < nb; j += 1024) {
        int lo = 0, hi = NPART;
        while (hi - lo > 1) { int mid = (lo + hi) >> 1; if (runoff[mid] <= j) lo = mid; else hi = mid; }
        int src = lo * CHUNK_E + soff[lo] + (j - runoff[lo]);
        int2 t = tmp[src];
        int key = ((t.x >> 20) & 63) * NCB + ((t.x & 0x3FFFF) >> CSH);
        int q = atomicAdd(&base[key], 1);
        unsigned qq = (unsigned)__float2int_rn(__int_as_float(t.y) * 4096.f);
        if (qq > 4095u) qq = 4095u;
        fin[bb0 + q] = ((unsigned)t.x & 0xFFFFFu) | (qq << 20);
    }
}

// ---- x0h bf16-packed: uint j of row r = comps (2j, 2j+1) ----
__global__ void convert_kernel(const float2* __restrict__ user, const float2* __restrict__ item,
                               unsigned* __restrict__ xh2) {
    int i = blockIdx.x * blockDim.x + threadIdx.x;   // = row*32 + j
    if (i >= NTOT * 32) return;
    float2 v = (i < NUSERS * 32) ? user[i] : item[i - NUSERS * 32];
    xh2[i] = (unsigned)benc(v.x) | ((unsigned)benc(v.y) << 16);
}

// ---- SpMM: 8-lane oct owns 4 rows; register acc; uint4 edge loads (4/load). ----
__global__ void __launch_bounds__(256)
spmm4_kernel(const int* __restrict__ optr, const unsigned* __restrict__ ed,
             const uint4* __restrict__ xin, uint4* __restrict__ yout,
             const uint4* __restrict__ x0h, const uint4* __restrict__ y1,
             float4* __restrict__ out, int last) {
    int wid  = blockIdx.x * 4 + (threadIdx.x >> 6);
    int lane = threadIdx.x & 63;
    int g    = wid * 8 + (lane >> 3);          // og id, < NOCT
    int s    = lane & 7;
    int i    = optr[g];
    int end  = optr[g + 1];
    const float SCL = 1.f / 4096.f;
    float4 A00 = {0,0,0,0}, A01 = {0,0,0,0};
    float4 A10 = {0,0,0,0}, A11 = {0,0,0,0};
    float4 A20 = {0,0,0,0}, A21 = {0,0,0,0};
    float4 A30 = {0,0,0,0}, A31 = {0,0,0,0};

#define PROC(E, G) do { \
        float v  = (float)((E) >> 20) * SCL; \
        int   k  = ((E) >> 18) & 3; \
        float s0 = (k == 0) ? v : 0.f, s1 = (k == 1) ? v : 0.f; \
        float s2 = (k == 2) ? v : 0.f, s3 = (k == 3) ? v : 0.f; \
        float f0 = blo((G).x), f1 = bhi((G).x), f2 = blo((G).y), f3 = bhi((G).y); \
        float f4_ = blo((G).z), f5 = bhi((G).z), f6 = blo((G).w), f7 = bhi((G).w); \
        A00.x += s0*f0; A00.y += s0*f1; A00.z += s0*f2; A00.w += s0*f3; \
        A01.x += s0*f4_; A01.y += s0*f5; A01.z += s0*f6; A01.w += s0*f7; \
        A10.x += s1*f0; A10.y += s1*f1; A10.z += s1*f2; A10.w += s1*f3; \
        A11.x += s1*f4_; A11.y += s1*f5; A11.z += s1*f6; A11.w += s1*f7; \
        A20.x += s2*f0; A20.y += s2*f1; A20.z += s2*f2; A20.w += s2*f3; \
        A21.x += s2*f4_; A21.y += s2*f5; A21.z += s2*f6; A21.w += s2*f7; \
        A30.x += s3*f0; A30.y += s3*f1; A30.z += s3*f2; A30.w += s3*f3; \
        A31.x += s3*f4_; A31.y += s3*f5; A31.z += s3*f6; A31.w += s3*f7; \
    } while (0)

    // scalar prologue to 16B alignment of ed+i
    while (i < end && (i & 3)) {
        unsigned e = ed[i];
        uint4 gg = xin[(size_t)(e & 0x3FFFF) * 8 + s];
        PROC(e, gg);
        ++i;
    }
    // main: 4 edges per uint4 load
    for (; i + 4 <= end; i += 4) {
        uint4 E4 = *(const uint4*)(ed + i);
        uint4 g0 = xin[(size_t)(E4.x & 0x3FFFF) * 8 + s];
        uint4 g1 = xin[(size_t)(E4.y & 0x3FFFF) * 8 + s];
        uint4 g2 = xin[(size_t)(E4.z & 0x3FFFF) * 8 + s];
        uint4 g3 = xin[(size_t)(E4.w & 0x3FFFF) * 8 + s];
        PROC(E4.x, g0); PROC(E4.y, g1); PROC(E4.z, g2); PROC(E4.w, g3);
    }
    for (; i < end; ++i) {
        unsigned e = ed[i];
        uint4 gg = xin[(size_t)(e & 0x3FFFF) * 8 + s];
        PROC(e, gg);
    }
#undef PROC

    if (!last) {
#define EPI(K, AK0, AK1) do { \
        int r = g * 4 + (K); \
        if (r < NTOT) { \
            uint4 o; \
            o.x = (unsigned)benc(AK0.x) | ((unsigned)benc(AK0.y) << 16); \
            o.y = (unsigned)benc(AK0.z) | ((unsigned)benc(AK0.w) << 16); \
            o.z = (unsigned)benc(AK1.x) | ((unsigned)benc(AK1.y) << 16); \
            o.w = (unsigned)benc(AK1.z) | ((unsigned)benc(AK1.w) << 16); \
            yout[(size_t)r * 8 + s] = o; \
        } \
    } while (0)
        EPI(0, A00, A01); EPI(1, A10, A11); EPI(2, A20, A21); EPI(3, A30, A31);
#undef EPI
    } else {
#define EPI(K, AK0, AK1) do { \
        int r = g * 4 + (K); \
        if (r < NTOT) { \
            uint4 u0 = x0h[(size_t)r * 8 + s]; \
            uint4 u1 = y1[(size_t)r * 8 + s]; \
            uint4 u2 = xin[(size_t)r * 8 + s]; \
            size_t f4 = (size_t)r * 16 + 2 * s; \
            float4 oa, ob; \
            oa.x = 0.25f * (blo(u0.x) + blo(u1.x) + blo(u2.x) + AK0.x); \
            oa.y = 0.25f * (bhi(u0.x) + bhi(u1.x) + bhi(u2.x) + AK0.y); \
            oa.z = 0.25f * (blo(u0.y) + blo(u1.y) + blo(u2.y) + AK0.z); \
            oa.w = 0.25f * (bhi(u0.y) + bhi(u1.y) + bhi(u2.y) + AK0.w); \
            ob.x = 0.25f * (blo(u0.z) + blo(u1.z) + blo(u2.z) + AK1.x); \
            ob.y = 0.25f * (bhi(u0.z) + bhi(u1.z) + bhi(u2.z) + AK1.y); \
            ob.z = 0.25f * (blo(u0.w) + blo(u1.w) + blo(u2.w) + AK1.z); \
            ob.w = 0.25f * (bhi(u0.w) + bhi(u1.w) + bhi(u2.w) + AK1.w); \
            out[f4]     = oa; \
            out[f4 + 1] = ob; \
        } \
    } while (0)
        EPI(0, A00, A01); EPI(1, A10, A11); EPI(2, A20, A21); EPI(3, A30, A31);
#undef EPI
    }
}

extern "C" void kernel_launch(void* const* d_in, const int* in_sizes, int n_in,
                              void* d_out, int out_size, void* d_ws, size_t ws_size,
                              hipStream_t stream) {
    const float* user = (const float*)d_in[0];
    const float* item = (const float*)d_in[1];
    const float* vals = (const float*)d_in[2];
    const int*   rows = (const int*)d_in[3];
    const int*   cols = (const int*)d_in[4];
    float* out = (float*)d_out;

    // ws layout (~81 MB): X 38.4M (tmp until partBF; then bufB|bufC) | fin 19.2M |
    // bufX 19.2M | cntmat 1.37M | runoffT 1.38M | segoff 1.37M | optr 150K |
    // colTotal | bptr
    char* w = (char*)d_ws;
    char*     X        = w;            w += (size_t)NNZ_E * 8;
    unsigned* fin      = (unsigned*)w; w += (size_t)NNZ_E * 4;
    unsigned* bufX     = (unsigned*)w; w += (size_t)NTOT * DIM * 2;   // x0h, persistent
    int*      cntmat   = (int*)w;      w += (size_t)NPART * NBUCK * 4;
    int*      runoffT  = (int*)w;      w += (size_t)NBUCK * (NPART + 1) * 4;
    int*      segoff   = (int*)w;      w += (size_t)NPART * NBUCK * 4;
    int*      optr     = (int*)w;      w += (size_t)(NOCT + 1) * 4;
    int*      colTotal = (int*)w;      w += (size_t)NBUCK * 4;
    int*      bptr     = (int*)w;

    int2*     tmp  = (int2*)X;                                  // dead after partBF
    unsigned* bufB = (unsigned*)X;                              // y1h
    unsigned* bufC = (unsigned*)(X + (size_t)NTOT * DIM * 2);   // y2h

    const int blk = 256;
    const int gConv = (NTOT * 32 + blk - 1) / blk;       // 18750
    const int gSpmm = NOCT / 32;                         // 1172 (4 waves, 8 ogs/wave)

    partA2_kernel<<<NPART, 512, 0, stream>>>(rows, cols, vals, cntmat, segoff, tmp);
    colscan1_kernel<<<NBUCK, 1024, 0, stream>>>(cntmat, runoffT, colTotal);
    colscan2_kernel<<<1, 1024, 0, stream>>>(colTotal, bptr);
    partBF_kernel<<<NBUCK, 1024, 0, stream>>>(bptr, runoffT, segoff, tmp, fin, optr);

    convert_kernel<<<gConv, blk, 0, stream>>>((const float2*)user, (const float2*)item, bufX);

    // tmp dead from here; bufB/bufC occupy its space.
    spmm4_kernel<<<gSpmm, blk, 0, stream>>>(optr, fin, (const uint4*)bufX, (uint4*)bufB,
                                            (const uint4*)bufX, (const uint4*)bufB,
                                            (float4*)out, 0);   // y1 = bufB
    spmm4_kernel<<<gSpmm, blk, 0, stream>>>(optr, fin, (const uint4*)bufB, (uint4*)bufC,
                                            (const uint4*)bufX, (const uint4*)bufB,
                                            (float4*)out, 0);   // y2 = bufC
    spmm4_kernel<<<gSpmm, blk, 0, stream>>>(optr, fin, (const uint4*)bufC, (uint4*)bufC,
                                            (const uint4*)bufX, (const uint4*)bufB,
                                            (float4*)out, 1);   // fused mean -> out
}